// Round 12
// baseline (138.881 us; speedup 1.0000x reference)
//
#include <hip/hip_runtime.h>

#define DIM           1024
#define BLK           64
#define NB            16      // DIM/BLK
#define RT            32      // rows per tile (DOUBLED vs R6-R11)
#define MAIN_THREADS  1024    // 16 waves; wave w owns block w
#define NWG           256     // persistent
#define TPW           8       // tiles per WG (65536/32/256)
#define P68           68      // padded LDS row for expm
#define BFRAG_STRIDE  512     // ushorts per (k,n0,h) B-frag block

typedef float  f32x4  __attribute__((ext_vector_type(4)));
typedef unsigned uintx2 __attribute__((ext_vector_type(2)));
typedef int    i32x4  __attribute__((ext_vector_type(4)));
typedef short  bf16x8 __attribute__((ext_vector_type(8)));

// f32 -> bf16 bits, round-to-nearest-even
static __device__ __forceinline__ ushort f2bf(float f) {
    union { float f; unsigned u; } v; v.f = f;
    unsigned r = v.u + 0x7fffu + ((v.u >> 16) & 1u);
    return (ushort)(r >> 16);
}
static __device__ __forceinline__ float bfhi2f(unsigned hi_bits) {
    union { unsigned u; float f; } v; v.u = hi_bits & 0xffff0000u; return v.f;
}
static __device__ __forceinline__ float bflo2f(unsigned lo_bits) {
    union { unsigned u; float f; } v; v.u = lo_bits << 16; return v.f;
}
// packed f32x2 -> bf16x2 (single VALU op, RTNE)
static __device__ __forceinline__ unsigned cvt_pk(float lo, float hi) {
    unsigned r;
    asm("v_cvt_pk_bf16_f32 %0, %1, %2" : "=v"(r) : "v"(lo), "v"(hi));
    return r;
}

#define WAITL()   asm volatile("s_waitcnt lgkmcnt(0)" ::: "memory")
#define SBAR()    __builtin_amdgcn_s_barrier()

// ---------------------------------------------------------------------------
// Kernel 1 (fused): blocks 0..15 = per-block expm (Taylor to A^7/7!);
// block 16 = perm decode -> INVERSE permutation pinv (pinv[perm[j]] = j).
// Btl[((k*4+n)*2+h)*512 + g*128 + m*8 + j] = B_k[h*32+g*8+j][n*16+m], bf16.
// ---------------------------------------------------------------------------
__global__ __launch_bounds__(512) void expm_kernel(
        const float* __restrict__ skew, ushort* __restrict__ Btl,
        const int* __restrict__ praw, int* __restrict__ pinv) {
    __shared__ float Asm[BLK][P68];
    __shared__ float Tb[2][BLK][P68];
    __shared__ float Rm[BLK][P68];
    const int tid = threadIdx.x;

    if (blockIdx.x == NB) {                 // ---- perm decode -> inverse ----
        __shared__ int zc;
        if (tid == 0) zc = 0;
        __syncthreads();
        int local = 0;
        for (int i = tid; i < DIM; i += 512)
            if (praw[i] == 0) local++;
        if (local) atomicAdd(&zc, local);
        __syncthreads();
        const bool is64 = (zc > 100);       // i64 read as i32: ~512 zero hi-words
        const long long* p64 = (const long long*)praw;
        for (int i = tid; i < DIM; i += 512) {
            const int v = is64 ? (int)p64[i] : praw[i];
            pinv[v] = i;
        }
        return;
    }

    const int k = blockIdx.x;
    const float* P = skew + (size_t)k * (BLK * BLK);

    for (int e = tid; e < BLK * BLK; e += 512) {
        const int i = e >> 6, j = e & 63;
        const float a = P[i * BLK + j] - P[j * BLK + i];   // A = P - P^T
        Asm[i][j]   = a;
        Tb[0][i][j] = a;                                   // T_1 = A
        Rm[i][j]    = a + (i == j ? 1.0f : 0.0f);          // R = I + A
    }
    __syncthreads();

    const int i0 = (tid >> 4) * 2;
    const int j0 = (tid & 15) * 4;

    for (int n = 2; n <= 7; ++n) {   // T_n = T_{n-1} * A / n ; R += T_n
        const float invn = 1.0f / (float)n;
        const float (*Tc)[P68] = Tb[n & 1];
        float       (*Tn)[P68] = Tb[1 - (n & 1)];
        f32x4 acc0 = {0.f, 0.f, 0.f, 0.f}, acc1 = {0.f, 0.f, 0.f, 0.f};
        for (int b = 0; b < BLK; ++b) {
            const f32x4 av = *(const f32x4*)&Asm[b][j0];
            acc0 += Tc[i0][b]     * av;
            acc1 += Tc[i0 + 1][b] * av;
        }
        acc0 *= invn; acc1 *= invn;
        *(f32x4*)&Tn[i0][j0]     = acc0;
        *(f32x4*)&Tn[i0 + 1][j0] = acc1;
        f32x4 r0 = *(const f32x4*)&Rm[i0][j0];     r0 += acc0; *(f32x4*)&Rm[i0][j0]     = r0;
        f32x4 r1 = *(const f32x4*)&Rm[i0 + 1][j0]; r1 += acc1; *(f32x4*)&Rm[i0 + 1][j0] = r1;
        __syncthreads();
    }

    for (int e = tid; e < BLK * BLK; e += 512) {
        const int b = e >> 6, c = e & 63;        // value B[b][c]
        const int n = c >> 4, m = c & 15;
        const int h = b >> 5, g = (b >> 3) & 3, j = b & 7;
        const size_t idx = (size_t)((k * 4 + n) * 2 + h) * BFRAG_STRIDE
                         + g * 128 + m * 8 + j;
        Btl[idx] = (ushort)f2bf(Rm[b][c]);
    }
}

// ---------------------------------------------------------------------------
// Kernel 2: persistent main, RT=32 (single-variable test vs R9's RT=16).
// 256 WGs x 8 tiles of 32 rows; 1024 threads = 16 waves; wave w owns block w.
// Per tile (ONE barrier, phase length doubled, barrier count halved):
//   - convert both 16-row halves of A(it) (frees 32 prefetch regs)
//   - prefetch A(it+1): 8x f32x4 = 16 KB per wave-set in flight
//   - half0: 8x MFMA -> scatter 16x ds_write_b16 (pre-permuted bf16 y')
//   - half1: same
//   - epilogue(it-1) from other buffer: wave w -> rows {2w,2w+1}, 8x
//     {uintx2 LDS read + dual-row 512B-segment f32x4 store}
//   - WAITL + SBAR
// VGPR budget: bfr 32 + aP 32 + cvt 16 + acc 16 + jb/addr ~20 = ~116 < 256
// (launch_bounds(1024,1); R8 lesson: never cap below live-range peak).
// LDS: 2 x 64 KB bf16 y' = 128 KB (1 WG/CU).
// ---------------------------------------------------------------------------
__global__ __launch_bounds__(MAIN_THREADS, 1) void gsl_main_kernel(
        const float* __restrict__ x, const ushort* __restrict__ Btl,
        const int* __restrict__ pinv, float* __restrict__ out) {
    __shared__ ushort ybuf[2][RT * DIM];   // 2 x 64 KB bf16 permuted-y tiles

    const int tid  = threadIdx.x;
    const int lane = tid & 63;
    const int w    = tid >> 6;         // wave 0..15 = block id
    const int g    = lane >> 4;        // 0..3
    const int m16  = lane & 15;

    // B-frags for block w: 8 x bf16x8 = 32 regs (persistent)
    bf16x8 bfr[4][2];
#pragma unroll
    for (int n = 0; n < 4; ++n)
#pragma unroll
        for (int h = 0; h < 2; ++h)
            bfr[n][h] = *(const bf16x8*)(Btl +
                (size_t)((w * 4 + n) * 2 + h) * BFRAG_STRIDE + lane * 8);

    // Permuted scatter columns: j = pinv[w*64 + n*16 + m16]
    int jb[4];
#pragma unroll
    for (int n = 0; n < 4; ++n)
        jb[n] = pinv[w * 64 + n * 16 + m16] * 2;   // byte offset within row

    const int tile0 = blockIdx.x * TPW;
    const float* xw = x + w * 64 + g * 8;          // + row*1024 per use

    // epilogue geometry: wave w -> rows {2w, 2w+1}; lane<32 row 2w, else 2w+1
    const int q32  = lane & 31;
    const int erow = 2 * w + (lane >> 5);

    // A(tile0) prefetch: halves h=0,1 -> rows tile*32 + h*16 + m16
    f32x4 aP[8];
#pragma unroll
    for (int h = 0; h < 2; ++h) {
        const float* xp = xw + (size_t)(tile0 * RT + h * 16 + m16) * DIM;
        aP[h * 4 + 0] = *(const f32x4*)(xp);
        aP[h * 4 + 1] = *(const f32x4*)(xp + 4);
        aP[h * 4 + 2] = *(const f32x4*)(xp + 32);
        aP[h * 4 + 3] = *(const f32x4*)(xp + 36);
    }

    for (int it = 0; it < TPW; ++it) {
        char* const yc = (char*)ybuf[it & 1];

        // convert A(it), both halves (frees aP for the prefetch)
        i32x4 pl0, ph0, pl1, ph1;
        pl0[0] = cvt_pk(aP[0][0], aP[0][1]); pl0[1] = cvt_pk(aP[0][2], aP[0][3]);
        pl0[2] = cvt_pk(aP[1][0], aP[1][1]); pl0[3] = cvt_pk(aP[1][2], aP[1][3]);
        ph0[0] = cvt_pk(aP[2][0], aP[2][1]); ph0[1] = cvt_pk(aP[2][2], aP[2][3]);
        ph0[2] = cvt_pk(aP[3][0], aP[3][1]); ph0[3] = cvt_pk(aP[3][2], aP[3][3]);
        pl1[0] = cvt_pk(aP[4][0], aP[4][1]); pl1[1] = cvt_pk(aP[4][2], aP[4][3]);
        pl1[2] = cvt_pk(aP[5][0], aP[5][1]); pl1[3] = cvt_pk(aP[5][2], aP[5][3]);
        ph1[0] = cvt_pk(aP[6][0], aP[6][1]); ph1[1] = cvt_pk(aP[6][2], aP[6][3]);
        ph1[2] = cvt_pk(aP[7][0], aP[7][1]); ph1[3] = cvt_pk(aP[7][2], aP[7][3]);

        if (it + 1 < TPW) {            // prefetch A(it+1)
#pragma unroll
            for (int h = 0; h < 2; ++h) {
                const float* xp = xw + (size_t)((tile0 + it + 1) * RT + h * 16 + m16) * DIM;
                aP[h * 4 + 0] = *(const f32x4*)(xp);
                aP[h * 4 + 1] = *(const f32x4*)(xp + 4);
                aP[h * 4 + 2] = *(const f32x4*)(xp + 32);
                aP[h * 4 + 3] = *(const f32x4*)(xp + 36);
            }
        }

        // ---- half 0: rows 0..15 of tile ----
        {
            const bf16x8 alo = __builtin_bit_cast(bf16x8, pl0);
            const bf16x8 ahi = __builtin_bit_cast(bf16x8, ph0);
            f32x4 acc[4];
#pragma unroll
            for (int n = 0; n < 4; ++n) acc[n] = (f32x4){0.f, 0.f, 0.f, 0.f};
#pragma unroll
            for (int n = 0; n < 4; ++n)
                acc[n] = __builtin_amdgcn_mfma_f32_16x16x32_bf16(alo, bfr[n][0], acc[n], 0, 0, 0);
#pragma unroll
            for (int n = 0; n < 4; ++n)
                acc[n] = __builtin_amdgcn_mfma_f32_16x16x32_bf16(ahi, bfr[n][1], acc[n], 0, 0, 0);
#pragma unroll
            for (int n = 0; n < 4; ++n)
#pragma unroll
                for (int i = 0; i < 4; ++i)
                    *(ushort*)(yc + (4 * g + i) * 2048 + jb[n]) = f2bf(acc[n][i]);
        }

        // ---- half 1: rows 16..31 of tile ----
        {
            const bf16x8 alo = __builtin_bit_cast(bf16x8, pl1);
            const bf16x8 ahi = __builtin_bit_cast(bf16x8, ph1);
            f32x4 acc[4];
#pragma unroll
            for (int n = 0; n < 4; ++n) acc[n] = (f32x4){0.f, 0.f, 0.f, 0.f};
#pragma unroll
            for (int n = 0; n < 4; ++n)
                acc[n] = __builtin_amdgcn_mfma_f32_16x16x32_bf16(alo, bfr[n][0], acc[n], 0, 0, 0);
#pragma unroll
            for (int n = 0; n < 4; ++n)
                acc[n] = __builtin_amdgcn_mfma_f32_16x16x32_bf16(ahi, bfr[n][1], acc[n], 0, 0, 0);
#pragma unroll
            for (int n = 0; n < 4; ++n)
#pragma unroll
                for (int i = 0; i < 4; ++i)
                    *(ushort*)(yc + (16 + 4 * g + i) * 2048 + jb[n]) = f2bf(acc[n][i]);
        }

        // ---- epilogue(it-1): rows {2w, 2w+1}, dual-row 512B segments ----
        if (it) {
            const char* yp = (const char*)ybuf[(it & 1) ^ 1] + erow * 2048;
            float* orow = out + (size_t)((tile0 + it - 1) * RT + erow) * DIM;
#pragma unroll
            for (int s = 0; s < 8; ++s) {
                const int e = q32 * 4 + s * 128;
                const uintx2 u = *(const uintx2*)(yp + e * 2);
                f32x4 v;
                v[0] = bflo2f(u[0]); v[1] = bfhi2f(u[0]);
                v[2] = bflo2f(u[1]); v[3] = bfhi2f(u[1]);
                *(f32x4*)(orow + e) = v;
            }
        }

        WAITL(); SBAR();               // scatter visible; epilogue reads done
    }

    // final epilogue: tile TPW-1
    {
        const char* yp = (const char*)ybuf[(TPW - 1) & 1] + erow * 2048;
        float* orow = out + (size_t)((tile0 + TPW - 1) * RT + erow) * DIM;
#pragma unroll
        for (int s = 0; s < 8; ++s) {
            const int e = q32 * 4 + s * 128;
            const uintx2 u = *(const uintx2*)(yp + e * 2);
            f32x4 v;
            v[0] = bflo2f(u[0]); v[1] = bfhi2f(u[0]);
            v[2] = bflo2f(u[1]); v[3] = bfhi2f(u[1]);
            *(f32x4*)(orow + e) = v;
        }
    }
}

// ---------------------------------------------------------------------------
extern "C" void kernel_launch(void* const* d_in, const int* in_sizes, int n_in,
                              void* d_out, int out_size, void* d_ws, size_t ws_size,
                              hipStream_t stream) {
    const float* x    = (const float*)d_in[0];   // [65536, 1024] f32
    const float* skew = (const float*)d_in[1];   // [16, 64, 64] f32
    const int*   perm = (const int*)d_in[2];     // [1024] i32/i64 (detected)
    float* out = (float*)d_out;

    // ws: [0,128KB) Btl bf16 lane-linear; [128KB,+4KB) inverse perm i32
    ushort* Btl  = (ushort*)d_ws;
    int*    pinv = (int*)((char*)d_ws + (size_t)NB * BLK * BLK * sizeof(ushort));

    expm_kernel<<<NB + 1, 512, 0, stream>>>(skew, Btl, perm, pinv);
    gsl_main_kernel<<<NWG, MAIN_THREADS, 0, stream>>>(x, Btl, pinv, out);
}

// Round 13
// 138.625 us; speedup vs baseline: 1.0018x; 1.0018x over previous
//
#include <hip/hip_runtime.h>

#define DIM           1024
#define BLK           64
#define NB            16      // DIM/BLK
#define RT            16      // rows per tile
#define MAIN_THREADS  512     // 8 waves; wave w does blocks w, w+8 per tile
#define NWG           512     // 2 independent WGs per CU (the tested variable)
#define TPW           8       // tiles per WG (4096 / 512)
#define P68           68      // padded LDS row for expm
#define BFRAG_STRIDE  512     // ushorts per (k,n0,h) B-frag block

typedef float  f32x4  __attribute__((ext_vector_type(4)));
typedef unsigned uintx2 __attribute__((ext_vector_type(2)));
typedef int    i32x4  __attribute__((ext_vector_type(4)));
typedef short  bf16x8 __attribute__((ext_vector_type(8)));

// f32 -> bf16 bits, round-to-nearest-even
static __device__ __forceinline__ ushort f2bf(float f) {
    union { float f; unsigned u; } v; v.f = f;
    unsigned r = v.u + 0x7fffu + ((v.u >> 16) & 1u);
    return (ushort)(r >> 16);
}
static __device__ __forceinline__ float bfhi2f(unsigned hi_bits) {
    union { unsigned u; float f; } v; v.u = hi_bits & 0xffff0000u; return v.f;
}
static __device__ __forceinline__ float bflo2f(unsigned lo_bits) {
    union { unsigned u; float f; } v; v.u = lo_bits << 16; return v.f;
}
// packed f32x2 -> bf16x2 (single VALU op, RTNE)
static __device__ __forceinline__ unsigned cvt_pk(float lo, float hi) {
    unsigned r;
    asm("v_cvt_pk_bf16_f32 %0, %1, %2" : "=v"(r) : "v"(lo), "v"(hi));
    return r;
}

#define WAITL()   asm volatile("s_waitcnt lgkmcnt(0)" ::: "memory")
#define SBAR()    __builtin_amdgcn_s_barrier()

// ---------------------------------------------------------------------------
// Kernel 1 (fused): blocks 0..15 = per-block expm (Taylor to A^7/7!);
// block 16 = perm decode -> INVERSE permutation pinv (pinv[perm[j]] = j).
// Btl[((k*4+n)*2+h)*512 + g*128 + m*8 + j] = B_k[h*32+g*8+j][n*16+m], bf16.
// ---------------------------------------------------------------------------
__global__ __launch_bounds__(512) void expm_kernel(
        const float* __restrict__ skew, ushort* __restrict__ Btl,
        const int* __restrict__ praw, int* __restrict__ pinv) {
    __shared__ float Asm[BLK][P68];
    __shared__ float Tb[2][BLK][P68];
    __shared__ float Rm[BLK][P68];
    const int tid = threadIdx.x;

    if (blockIdx.x == NB) {                 // ---- perm decode -> inverse ----
        __shared__ int zc;
        if (tid == 0) zc = 0;
        __syncthreads();
        int local = 0;
        for (int i = tid; i < DIM; i += 512)
            if (praw[i] == 0) local++;
        if (local) atomicAdd(&zc, local);
        __syncthreads();
        const bool is64 = (zc > 100);       // i64 read as i32: ~512 zero hi-words
        const long long* p64 = (const long long*)praw;
        for (int i = tid; i < DIM; i += 512) {
            const int v = is64 ? (int)p64[i] : praw[i];
            pinv[v] = i;
        }
        return;
    }

    const int k = blockIdx.x;
    const float* P = skew + (size_t)k * (BLK * BLK);

    for (int e = tid; e < BLK * BLK; e += 512) {
        const int i = e >> 6, j = e & 63;
        const float a = P[i * BLK + j] - P[j * BLK + i];   // A = P - P^T
        Asm[i][j]   = a;
        Tb[0][i][j] = a;                                   // T_1 = A
        Rm[i][j]    = a + (i == j ? 1.0f : 0.0f);          // R = I + A
    }
    __syncthreads();

    const int i0 = (tid >> 4) * 2;
    const int j0 = (tid & 15) * 4;

    for (int n = 2; n <= 7; ++n) {   // T_n = T_{n-1} * A / n ; R += T_n
        const float invn = 1.0f / (float)n;
        const float (*Tc)[P68] = Tb[n & 1];
        float       (*Tn)[P68] = Tb[1 - (n & 1)];
        f32x4 acc0 = {0.f, 0.f, 0.f, 0.f}, acc1 = {0.f, 0.f, 0.f, 0.f};
        for (int b = 0; b < BLK; ++b) {
            const f32x4 av = *(const f32x4*)&Asm[b][j0];
            acc0 += Tc[i0][b]     * av;
            acc1 += Tc[i0 + 1][b] * av;
        }
        acc0 *= invn; acc1 *= invn;
        *(f32x4*)&Tn[i0][j0]     = acc0;
        *(f32x4*)&Tn[i0 + 1][j0] = acc1;
        f32x4 r0 = *(const f32x4*)&Rm[i0][j0];     r0 += acc0; *(f32x4*)&Rm[i0][j0]     = r0;
        f32x4 r1 = *(const f32x4*)&Rm[i0 + 1][j0]; r1 += acc1; *(f32x4*)&Rm[i0 + 1][j0] = r1;
        __syncthreads();
    }

    for (int e = tid; e < BLK * BLK; e += 512) {
        const int b = e >> 6, c = e & 63;        // value B[b][c]
        const int n = c >> 4, m = c & 15;
        const int h = b >> 5, g = (b >> 3) & 3, j = b & 7;
        const size_t idx = (size_t)((k * 4 + n) * 2 + h) * BFRAG_STRIDE
                         + g * 128 + m * 8 + j;
        Btl[idx] = (ushort)f2bf(Rm[b][c]);
    }
}

// ---------------------------------------------------------------------------
// Kernel 2: persistent main, TWO INDEPENDENT WGs PER CU (the last untested
// structural lever). 512 WGs x 8 tiles; 512 threads = 8 waves.
// Wave w processes blocks w then w+8 per tile (rolled loop), RELOADING
// B-frags + jb from L2 per block (Btl = 128 KB, L2-permanent; 2 KB/block)
// instead of 64 persistent VGPRs -> VGPR ~95-100 -> 2 WGs co-resident
// (LDS 64 KB/WG). NO launch_bounds min-wave arg (R8 lesson: the (512,4)
// cap forced VGPR=64 + scratch spill; counter-proven).
// Per tile (ONE WAITL+SBAR, R9-proven):
//   bs=0: reload bfr/jb(w)   -> cvt aP -> prefetch aP=(it,w+8) -> MFMA ->
//         bf16 scatter into y'(it)
//   bs=1: reload bfr/jb(w+8) -> cvt aP -> prefetch aP=(it+1,w) -> MFMA ->
//         scatter
//   epilogue(it-1) from other buffer: wave w -> rows {2w,2w+1}, 8x dual-row
//   512B-segment stores; WAITL + SBAR.
// Mechanism under test: while WG-A is in its barrier-locked compute/LDS
// phase, co-resident WG-B issues HBM traffic -> continuous memory issue
// (what fill/copy kernels have and all 1-WG/CU variants lack).
// ---------------------------------------------------------------------------
__global__ __launch_bounds__(MAIN_THREADS) void gsl_main_kernel(
        const float* __restrict__ x, const ushort* __restrict__ Btl,
        const int* __restrict__ pinv, float* __restrict__ out) {
    __shared__ ushort ybuf[2][RT * DIM];   // 2 x 32 KB bf16 permuted-y tiles

    const int tid  = threadIdx.x;
    const int lane = tid & 63;
    const int w    = tid >> 6;         // wave 0..7
    const int g    = lane >> 4;        // 0..3
    const int m16  = lane & 15;

    const int tile0 = blockIdx.x * TPW;

    // epilogue geometry: wave w -> rows {2w, 2w+1}; lane<32 row 2w else 2w+1
    const int q32  = lane & 31;
    const int erow = 2 * w + (lane >> 5);

    // A prefetch for (tile0, block w)
    f32x4 aP0, aP1, aP2, aP3;
    {
        const float* xp = x + (size_t)(tile0 * RT + m16) * DIM + w * 64 + g * 8;
        aP0 = *(const f32x4*)(xp);      aP1 = *(const f32x4*)(xp + 4);
        aP2 = *(const f32x4*)(xp + 32); aP3 = *(const f32x4*)(xp + 36);
    }

    for (int it = 0; it < TPW; ++it) {
        char* const yc = (char*)ybuf[it & 1];

        for (int bs = 0; bs < 2; ++bs) {       // rolled: caps VGPR
            const int k = w + 8 * bs;

            // reload B-frags + scatter cols for block k (L2-hot, 2KB + 16B)
            bf16x8 bfr[4][2];
#pragma unroll
            for (int n = 0; n < 4; ++n)
#pragma unroll
                for (int h = 0; h < 2; ++h)
                    bfr[n][h] = *(const bf16x8*)(Btl +
                        (size_t)((k * 4 + n) * 2 + h) * BFRAG_STRIDE + lane * 8);
            int jb[4];
#pragma unroll
            for (int n = 0; n < 4; ++n)
                jb[n] = pinv[k * 64 + n * 16 + m16] * 2;

            // convert current aP (frees the 16 prefetch regs)
            i32x4 plo, phi;
            plo[0] = cvt_pk(aP0[0], aP0[1]); plo[1] = cvt_pk(aP0[2], aP0[3]);
            plo[2] = cvt_pk(aP1[0], aP1[1]); plo[3] = cvt_pk(aP1[2], aP1[3]);
            phi[0] = cvt_pk(aP2[0], aP2[1]); phi[1] = cvt_pk(aP2[2], aP2[3]);
            phi[2] = cvt_pk(aP3[0], aP3[1]); phi[3] = cvt_pk(aP3[2], aP3[3]);

            // prefetch next block-step's A: (it, w+8) at bs=0; (it+1, w) at bs=1
            const int nit = (bs == 0) ? it : it + 1;
            if (bs == 0 || it + 1 < TPW) {
                const float* xp = x + (size_t)((tile0 + nit) * RT + m16) * DIM
                                + (w + 8 * (1 - bs)) * 64 + g * 8;
                aP0 = *(const f32x4*)(xp);      aP1 = *(const f32x4*)(xp + 4);
                aP2 = *(const f32x4*)(xp + 32); aP3 = *(const f32x4*)(xp + 36);
            }

            const bf16x8 alo = __builtin_bit_cast(bf16x8, plo);
            const bf16x8 ahi = __builtin_bit_cast(bf16x8, phi);
            f32x4 acc[4];
#pragma unroll
            for (int n = 0; n < 4; ++n) acc[n] = (f32x4){0.f, 0.f, 0.f, 0.f};
#pragma unroll
            for (int n = 0; n < 4; ++n)
                acc[n] = __builtin_amdgcn_mfma_f32_16x16x32_bf16(alo, bfr[n][0], acc[n], 0, 0, 0);
#pragma unroll
            for (int n = 0; n < 4; ++n)
                acc[n] = __builtin_amdgcn_mfma_f32_16x16x32_bf16(ahi, bfr[n][1], acc[n], 0, 0, 0);

            // scatter into pre-permuted bf16 y'(it): row 4g+i, permuted col
#pragma unroll
            for (int n = 0; n < 4; ++n)
#pragma unroll
                for (int i = 0; i < 4; ++i)
                    *(ushort*)(yc + (4 * g + i) * 2048 + jb[n]) = f2bf(acc[n][i]);
        }

        // epilogue(it-1): rows {2w,2w+1}, dual-row 512B segments (clean shape)
        if (it) {
            const char* yp = (const char*)ybuf[(it & 1) ^ 1] + erow * 2048;
            float* orow = out + (size_t)((tile0 + it - 1) * RT + erow) * DIM;
#pragma unroll
            for (int s = 0; s < 8; ++s) {
                const int e = q32 * 4 + s * 128;
                const uintx2 u = *(const uintx2*)(yp + e * 2);
                f32x4 v;
                v[0] = bflo2f(u[0]); v[1] = bfhi2f(u[0]);
                v[2] = bflo2f(u[1]); v[3] = bfhi2f(u[1]);
                *(f32x4*)(orow + e) = v;
            }
        }

        WAITL(); SBAR();               // scatter visible; epilogue reads done
    }

    // final epilogue: tile TPW-1
    {
        const char* yp = (const char*)ybuf[(TPW - 1) & 1] + erow * 2048;
        float* orow = out + (size_t)((tile0 + TPW - 1) * RT + erow) * DIM;
#pragma unroll
        for (int s = 0; s < 8; ++s) {
            const int e = q32 * 4 + s * 128;
            const uintx2 u = *(const uintx2*)(yp + e * 2);
            f32x4 v;
            v[0] = bflo2f(u[0]); v[1] = bfhi2f(u[0]);
            v[2] = bflo2f(u[1]); v[3] = bfhi2f(u[1]);
            *(f32x4*)(orow + e) = v;
        }
    }
}

// ---------------------------------------------------------------------------
extern "C" void kernel_launch(void* const* d_in, const int* in_sizes, int n_in,
                              void* d_out, int out_size, void* d_ws, size_t ws_size,
                              hipStream_t stream) {
    const float* x    = (const float*)d_in[0];   // [65536, 1024] f32
    const float* skew = (const float*)d_in[1];   // [16, 64, 64] f32
    const int*   perm = (const int*)d_in[2];     // [1024] i32/i64 (detected)
    float* out = (float*)d_out;

    // ws: [0,128KB) Btl bf16 lane-linear; [128KB,+4KB) inverse perm i32
    ushort* Btl  = (ushort*)d_ws;
    int*    pinv = (int*)((char*)d_ws + (size_t)NB * BLK * BLK * sizeof(ushort));

    expm_kernel<<<NB + 1, 512, 0, stream>>>(skew, Btl, perm, pinv);
    gsl_main_kernel<<<NWG, MAIN_THREADS, 0, stream>>>(x, Btl, pinv, out);
}